// Round 8
// baseline (86.075 us; speedup 1.0000x reference)
//
#include <hip/hip_runtime.h>
#include <math.h>
#include <limits.h>

#define NN 8192
#define DD 128
#define BM 128        // rows per block (4 waves x 32)
#define BN 64         // cols per j-tile
#define NPART 16      // grid = 64*16 = 1024 blocks
#define JRANGE (NN / NPART)    // 512
#define NTILES (JRANGE / BN)   // 8
#define NIT (NTILES * 4)       // 32 pipelined (jt,c) steps

typedef __attribute__((ext_vector_type(4))) int i32x4;

// ws byte offsets
#define WS_PARTIAL 0                       // 1024 floats
#define WS_SCALE   4096                    // 1 float (mm)
#define WS_MD      8192                    // 8192 int2 = 64 KB
#define WS_HPK     (8192 + 65536)          // 32 KB int
#define WS_HNK     (WS_HPK + 32768)        // 32 KB int
#define WS_AH      (WS_HNK + 32768)        // 1 MB
#define WS_AL      (WS_AH + NN * DD)       // 1 MB

// pass 1: per-block absmax partials
__global__ __launch_bounds__(256)
void prep_k(const float* __restrict__ emb, float* __restrict__ partial) {
    int i = blockIdx.x * 256 + threadIdx.x;          // float4 index (1024 blocks)
    float4 v = reinterpret_cast<const float4*>(emb)[i];
    float m = fmaxf(fmaxf(fabsf(v.x), fabsf(v.y)), fmaxf(fabsf(v.z), fabsf(v.w)));
#pragma unroll
    for (int off = 1; off < 64; off <<= 1) m = fmaxf(m, __shfl_xor(m, off, 64));
    __shared__ float sm[4];
    if ((threadIdx.x & 63) == 0) sm[threadIdx.x >> 6] = m;
    __syncthreads();
    if (threadIdx.x == 0)
        partial[blockIdx.x] = fmaxf(fmaxf(sm[0], sm[1]), fmaxf(sm[2], sm[3]));
}

// pass 2: global amax reduce + i8 hi/lo quantize + int metadata + key init
__global__ __launch_bounds__(256)
void quantize_k(const float* __restrict__ emb, const int* __restrict__ lab,
                const float* __restrict__ partial, int* __restrict__ aH,
                int* __restrict__ aL, int2* __restrict__ md,
                int* __restrict__ hpK, int* __restrict__ hnK,
                float* __restrict__ scale) {
    __shared__ float sm[4];
    float m = fmaxf(fmaxf(partial[threadIdx.x], partial[threadIdx.x + 256]),
                    fmaxf(partial[threadIdx.x + 512], partial[threadIdx.x + 768]));
#pragma unroll
    for (int off = 1; off < 64; off <<= 1) m = fmaxf(m, __shfl_xor(m, off, 64));
    if ((threadIdx.x & 63) == 0) sm[threadIdx.x >> 6] = m;
    __syncthreads();
    float amax = fmaxf(fmaxf(fmaxf(sm[0], sm[1]), fmaxf(sm[2], sm[3])), 1e-30f);
    float sA  = amax * (1.0f / 127.0f);
    float inv = 127.0f / amax;
    float mm  = sA * sA * (1.0f / 128.0f);   // g_true = mm * g_int

    const int lane = threadIdx.x & 63;
    const int w    = threadIdx.x >> 6;
    const int half = lane >> 5;
    const int l32  = lane & 31;
    const int row  = blockIdx.x * 8 + w * 2 + half;

    float4 v = reinterpret_cast<const float4*>(emb)[row * 32 + l32];
    float s = 0.f;
    s = fmaf(v.x, v.x, s); s = fmaf(v.y, v.y, s);
    s = fmaf(v.z, v.z, s); s = fmaf(v.w, v.w, s);
#pragma unroll
    for (int off = 1; off < 32; off <<= 1) s += __shfl_xor(s, off, 64);

    int h = 0, l = 0;
#define QSTEP(X, K) { \
        float a = rintf((X) * inv); \
        a = fminf(fmaxf(a, -127.f), 127.f); \
        float r = fmaf(-a, sA, (X)); \
        float b = rintf(r * inv * 256.0f); \
        b = fminf(fmaxf(b, -127.f), 127.f); \
        h |= ((int)a & 255) << (8 * (K)); \
        l |= ((int)b & 255) << (8 * (K)); }
    QSTEP(v.x, 0) QSTEP(v.y, 1) QSTEP(v.z, 2) QSTEP(v.w, 3)
#undef QSTEP
    aH[row * 32 + l32] = h;
    aL[row * 32 + l32] = l;
    if (l32 == 0) md[row] = make_int2((int)rintf(s / mm), lab[row]);
    if (threadIdx.x < 8) {
        int r0 = blockIdx.x * 8 + threadIdx.x;
        hpK[r0] = INT_MIN;
        hnK[r0] = INT_MAX;
    }
    if (blockIdx.x == 0 && threadIdx.x == 0) scale[0] = mm;
}

__global__ __launch_bounds__(256, 2)
void hardest_k(const int* __restrict__ aH, const int* __restrict__ aL,
               const int2* __restrict__ md,
               int* __restrict__ hpK, int* __restrict__ hnK) {
    const int tid  = threadIdx.x;
    const int w    = tid >> 6;
    const int lane = tid & 63;
    const int lrow = lane & 15;
    const int lk   = lane >> 4;
    const int ib   = (int)blockIdx.x >> 4;    // 0..63
    const int part = (int)blockIdx.x & 15;    // 0..15
    const int i0   = ib * BM;
    const int jbeg = part * JRANGE;

    // persistent A fragments: 2 strips of 16 rows, K=128 in 2 chunks, hi+lo (32 VGPR)
    i32x4 ah[2][2], al[2][2];
#pragma unroll
    for (int s = 0; s < 2; ++s) {
        int row = i0 + w * 32 + s * 16 + lrow;
#pragma unroll
        for (int q = 0; q < 2; ++q) {
            ah[s][q] = *reinterpret_cast<const i32x4*>(&aH[row * 32 + q * 16 + lk * 4]);
            al[s][q] = *reinterpret_cast<const i32x4*>(&aL[row * 32 + q * 16 + lk * 4]);
        }
    }
    int li[2][4], hp[2][4], hn[2][4];
#pragma unroll
    for (int s = 0; s < 2; ++s)
#pragma unroll
        for (int t = 0; t < 4; ++t) {
            li[s][t] = md[i0 + w * 32 + s * 16 + lk * 4 + t].y;
            hp[s][t] = INT_MIN;
            hn[s][t] = INT_MAX;
        }

    // flattened (jt,c) space, 2-deep software pipeline on B loads
#define JROW(IT) (jbeg + ((IT) >> 2) * BN + ((IT) & 3) * 16 + lrow)
    int jr = JROW(0);
    i32x4 pbh0 = *reinterpret_cast<const i32x4*>(&aH[jr * 32 + 0  + lk * 4]);
    i32x4 pbh1 = *reinterpret_cast<const i32x4*>(&aH[jr * 32 + 16 + lk * 4]);
    i32x4 pbl0 = *reinterpret_cast<const i32x4*>(&aL[jr * 32 + 0  + lk * 4]);
    i32x4 pbl1 = *reinterpret_cast<const i32x4*>(&aL[jr * 32 + 16 + lk * 4]);
    int2  pmd  = md[jr];

    auto compute = [&](i32x4 bh0, i32x4 bh1, i32x4 bl0, i32x4 bl1, int2 mj) {
        i32x4 accA[2], accB[2];
        i32x4 zero = {0, 0, 0, 0};
#pragma unroll
        for (int s = 0; s < 2; ++s) { accA[s] = zero; accB[s] = zero; }
#pragma unroll
        for (int s = 0; s < 2; ++s) {
            accA[s] = __builtin_amdgcn_mfma_i32_16x16x64_i8(ah[s][0], bh0, accA[s], 0, 0, 0);
            accA[s] = __builtin_amdgcn_mfma_i32_16x16x64_i8(ah[s][1], bh1, accA[s], 0, 0, 0);
            accB[s] = __builtin_amdgcn_mfma_i32_16x16x64_i8(ah[s][0], bl0, accB[s], 0, 0, 0);
            accB[s] = __builtin_amdgcn_mfma_i32_16x16x64_i8(ah[s][1], bl1, accB[s], 0, 0, 0);
            accB[s] = __builtin_amdgcn_mfma_i32_16x16x64_i8(al[s][0], bh0, accB[s], 0, 0, 0);
            accB[s] = __builtin_amdgcn_mfma_i32_16x16x64_i8(al[s][1], bh1, accB[s], 0, 0, 0);
        }
        const int qs = mj.x, lj = mj.y;
#pragma unroll
        for (int s = 0; s < 2; ++s)
#pragma unroll
            for (int t = 0; t < 4; ++t) {
                int e = accA[s][t] * 256 + accB[s][t];   // exact, |e| < 2^30
                int g = qs - e;                          // (sqj - 2*dot)/mm, exact int
                bool same = (li[s][t] == lj);
                hp[s][t] = max(hp[s][t], same ? g : INT_MIN);
                hn[s][t] = min(hn[s][t], same ? INT_MAX : g);
            }
    };

#pragma unroll 4
    for (int it = 0; it < NIT - 1; ++it) {
        i32x4 bh0 = pbh0, bh1 = pbh1, bl0 = pbl0, bl1 = pbl1;
        int2  mj  = pmd;
        int jn = JROW(it + 1);
        pbh0 = *reinterpret_cast<const i32x4*>(&aH[jn * 32 + 0  + lk * 4]);
        pbh1 = *reinterpret_cast<const i32x4*>(&aH[jn * 32 + 16 + lk * 4]);
        pbl0 = *reinterpret_cast<const i32x4*>(&aL[jn * 32 + 0  + lk * 4]);
        pbl1 = *reinterpret_cast<const i32x4*>(&aL[jn * 32 + 16 + lk * 4]);
        pmd  = md[jn];
        compute(bh0, bh1, bl0, bl1, mj);
    }
    compute(pbh0, pbh1, pbl0, pbl1, pmd);
#undef JROW

    // reduce over the 16 column-lanes sharing each output row (int domain)
#pragma unroll
    for (int off = 1; off < 16; off <<= 1)
#pragma unroll
        for (int s = 0; s < 2; ++s)
#pragma unroll
            for (int t = 0; t < 4; ++t) {
                hp[s][t] = max(hp[s][t], __shfl_xor(hp[s][t], off, 64));
                hn[s][t] = min(hn[s][t], __shfl_xor(hn[s][t], off, 64));
            }
    if (lrow == 0) {
#pragma unroll
        for (int s = 0; s < 2; ++s)
#pragma unroll
            for (int t = 0; t < 4; ++t) {
                int i = i0 + w * 32 + s * 16 + lk * 4 + t;
                atomicMax(&hpK[i], hp[s][t]);   // order-independent => deterministic
                atomicMin(&hnK[i], hn[s][t]);
            }
    }
}

__global__ __launch_bounds__(1024)
void final_k(const int* __restrict__ hpK, const int* __restrict__ hnK,
             const int2* __restrict__ md, const float* __restrict__ scale,
             float* __restrict__ out) {
    const float mm = scale[0];
    float total = 0.f, cnt = 0.f;
    for (int i = threadIdx.x; i < NN; i += 1024) {
        float sqi = mm * (float)md[i].x;
        float hp2 = fmaf(mm, (float)hpK[i], sqi);   // d^2 = sq_i + mm*g
        float hn2 = fmaf(mm, (float)hnK[i], sqi);   // hn sentinel INT_MAX -> huge -> excluded
        float hpd = sqrtf(fmaxf(hp2, 0.f));
        float hnd = sqrtf(fmaxf(hn2, 0.f));
        float tl = hpd - hnd + 1.0f;
        if (tl > 0.f) { total += tl; cnt += 1.f; }
    }
#pragma unroll
    for (int off = 1; off < 64; off <<= 1) {
        total += __shfl_xor(total, off, 64);
        cnt   += __shfl_xor(cnt,   off, 64);
    }
    __shared__ float sT[16], sC[16];
    int wave = threadIdx.x >> 6;
    if ((threadIdx.x & 63) == 0) { sT[wave] = total; sC[wave] = cnt; }
    __syncthreads();
    if (threadIdx.x == 0) {
        float T = 0.f, Cn = 0.f;
#pragma unroll
        for (int k = 0; k < 16; ++k) { T += sT[k]; Cn += sC[k]; }
        out[0] = (Cn > 0.f) ? T / Cn : 0.f;
    }
}

extern "C" void kernel_launch(void* const* d_in, const int* in_sizes, int n_in,
                              void* d_out, int out_size, void* d_ws, size_t ws_size,
                              hipStream_t stream) {
    const float* emb = (const float*)d_in[0];
    const int*   lab = (const int*)d_in[1];
    char* ws = (char*)d_ws;
    float* partial = (float*)(ws + WS_PARTIAL);
    float* scale   = (float*)(ws + WS_SCALE);
    int2*  md      = (int2*)(ws + WS_MD);
    int*   hpK     = (int*)(ws + WS_HPK);
    int*   hnK     = (int*)(ws + WS_HNK);
    int*   aH      = (int*)(ws + WS_AH);
    int*   aL      = (int*)(ws + WS_AL);

    prep_k<<<dim3(1024), dim3(256), 0, stream>>>(emb, partial);
    quantize_k<<<dim3(NN / 8), dim3(256), 0, stream>>>(emb, lab, partial, aH, aL, md, hpK, hnK, scale);
    hardest_k<<<dim3((NN / BM) * NPART), dim3(256), 0, stream>>>(aH, aL, md, hpK, hnK);
    final_k<<<dim3(1), dim3(1024), 0, stream>>>(hpK, hnK, md, scale, (float*)d_out);
}

// Round 9
// 55.165 us; speedup vs baseline: 1.5603x; 1.5603x over previous
//
#include <hip/hip_runtime.h>
#include <math.h>

#define NN 8192
#define DD 128
#define BM 256        // rows per block (4 waves x 64)
#define BN 64         // cols per j-tile
#define NPART 16      // grid = 32*16 = 512 blocks (2 blocks/CU, single batch)
#define JRANGE (NN / NPART)    // 512
#define NTILES (JRANGE / BN)   // 8
#define NIT (NTILES * 4)       // 32 flattened (jt,c) steps

typedef __attribute__((ext_vector_type(4))) int i32x4;

// ws byte offsets
#define WS_SJC 0                          // 8192 * float4 = 128 KB
#define WS_HPK (NN * 16)                  // 32 KB (uint keys)
#define WS_HNK (WS_HPK + NN * 4)          // 32 KB
#define WS_AH  (WS_HNK + NN * 4)          // 1 MB
#define WS_AL  (WS_AH + NN * DD)          // 1 MB

// order-preserving float -> uint key (unsigned compare == float compare)
__device__ __forceinline__ unsigned fkey(float f) {
    unsigned u = __float_as_uint(f);
    return (u & 0x80000000u) ? ~u : (u | 0x80000000u);
}
__device__ __forceinline__ float fkey_inv(unsigned k) {
    unsigned u = (k & 0x80000000u) ? (k ^ 0x80000000u) : ~k;
    return __uint_as_float(u);
}

// fused: per-row sqnorm + absmax + i8 hi/lo quantize + metadata pack + key init
__global__ __launch_bounds__(256)
void prepq_k(const float* __restrict__ emb, const int* __restrict__ lab,
             float4* __restrict__ sjc, unsigned* __restrict__ hpK,
             unsigned* __restrict__ hnK, int* __restrict__ aH, int* __restrict__ aL) {
    const int lane = threadIdx.x & 63;
    const int w    = threadIdx.x >> 6;
    const int half = lane >> 5;
    const int l32  = lane & 31;
    const int row  = blockIdx.x * 8 + w * 2 + half;

    float4 v = reinterpret_cast<const float4*>(emb)[row * 32 + l32];
    float s = 0.f, m = 0.f;
    s = fmaf(v.x, v.x, s); m = fmaxf(m, fabsf(v.x));
    s = fmaf(v.y, v.y, s); m = fmaxf(m, fabsf(v.y));
    s = fmaf(v.z, v.z, s); m = fmaxf(m, fabsf(v.z));
    s = fmaf(v.w, v.w, s); m = fmaxf(m, fabsf(v.w));
#pragma unroll
    for (int off = 1; off < 32; off <<= 1) {   // stays within the 32-lane half
        s += __shfl_xor(s, off, 64);
        m = fmaxf(m, __shfl_xor(m, off, 64));
    }
    m = fmaxf(m, 1e-30f);
    float sA  = m * (1.0f / 127.0f);
    float inv = 127.0f / m;
    int h = 0, l = 0;
#define QSTEP(X, K) { \
        float a = rintf((X) * inv); \
        a = fminf(fmaxf(a, -127.f), 127.f); \
        float r = fmaf(-a, sA, (X)); \
        float b = rintf(r * inv * 256.0f); \
        b = fminf(fmaxf(b, -127.f), 127.f); \
        h |= ((int)a & 255) << (8 * (K)); \
        l |= ((int)b & 255) << (8 * (K)); }
    QSTEP(v.x, 0) QSTEP(v.y, 1) QSTEP(v.z, 2) QSTEP(v.w, 3)
#undef QSTEP
    aH[row * 32 + l32] = h;
    aL[row * 32 + l32] = l;
    if (l32 == 0) {
        // ci = sA * sqrt(2)/16 so ci_i*ci_j = 2*sAi*sAj/256
        sjc[row] = make_float4(s, sA * 0.08838834764831845f,
                               __int_as_float(lab[row]), 0.f);
    }
    if (threadIdx.x < 8) {
        int r0 = blockIdx.x * 8 + threadIdx.x;
        hpK[r0] = 0x007FFFFFu;   // fkey(-inf)
        hnK[r0] = 0xFF800000u;   // fkey(+inf)
    }
}

__global__ __launch_bounds__(256, 2)
void hardest_k(const int* __restrict__ aH, const int* __restrict__ aL,
               const float4* __restrict__ sjc,
               unsigned* __restrict__ hpK, unsigned* __restrict__ hnK) {
    const int tid  = threadIdx.x;
    const int w    = tid >> 6;
    const int lane = tid & 63;
    const int lrow = lane & 15;
    const int lk   = lane >> 4;
    const int ib   = (int)blockIdx.x >> 4;    // 0..31
    const int part = (int)blockIdx.x & 15;    // 0..15
    const int i0   = ib * BM;
    const int jbeg = part * JRANGE;

    // persistent A fragments: 4 strips of 16 rows, K=128 in 2 chunks, hi+lo (64 VGPR)
    i32x4 ah[4][2], al[4][2];
#pragma unroll
    for (int s = 0; s < 4; ++s) {
        int row = i0 + w * 64 + s * 16 + lrow;
#pragma unroll
        for (int q = 0; q < 2; ++q) {
            ah[s][q] = *reinterpret_cast<const i32x4*>(&aH[row * 32 + q * 16 + lk * 4]);
            al[s][q] = *reinterpret_cast<const i32x4*>(&aL[row * 32 + q * 16 + lk * 4]);
        }
    }
    int   li[4][4];
    float cih[4][4], hpg[4][4], hng[4][4];
#pragma unroll
    for (int s = 0; s < 4; ++s)
#pragma unroll
        for (int t = 0; t < 4; ++t) {
            float4 md = sjc[i0 + w * 64 + s * 16 + lk * 4 + t];
            li[s][t]  = __float_as_int(md.z);
            cih[s][t] = md.y;
            hpg[s][t] = -INFINITY;
            hng[s][t] =  INFINITY;
        }

    // flattened (jt,c) iteration: jrow for step IT
#define JROWF(IT) (jbeg + ((IT) >> 2) * BN + ((IT) & 3) * 16 + lrow)

    // two named register buffers (static names -> no scratch, no sinking)
    i32x4 Ah0, Ah1, Al0, Al1; float4 Asv;
    i32x4 Bh0, Bh1, Bl0, Bl1; float4 Bsv;

#define LOADJ(P, IT) { \
        int jr_ = JROWF(IT); \
        P##h0 = *reinterpret_cast<const i32x4*>(&aH[jr_ * 32 + 0  + lk * 4]); \
        P##h1 = *reinterpret_cast<const i32x4*>(&aH[jr_ * 32 + 16 + lk * 4]); \
        P##l0 = *reinterpret_cast<const i32x4*>(&aL[jr_ * 32 + 0  + lk * 4]); \
        P##l1 = *reinterpret_cast<const i32x4*>(&aL[jr_ * 32 + 16 + lk * 4]); \
        P##sv = sjc[jr_]; }

#define COMPUTE(P) { \
        i32x4 accA[4], accB[4]; \
        i32x4 zero_ = {0, 0, 0, 0}; \
        _Pragma("unroll") \
        for (int s = 0; s < 4; ++s) { accA[s] = zero_; accB[s] = zero_; } \
        _Pragma("unroll") \
        for (int s = 0; s < 4; ++s) { \
            accA[s] = __builtin_amdgcn_mfma_i32_16x16x64_i8(ah[s][0], P##h0, accA[s], 0, 0, 0); \
            accA[s] = __builtin_amdgcn_mfma_i32_16x16x64_i8(ah[s][1], P##h1, accA[s], 0, 0, 0); \
            accB[s] = __builtin_amdgcn_mfma_i32_16x16x64_i8(ah[s][0], P##l0, accB[s], 0, 0, 0); \
            accB[s] = __builtin_amdgcn_mfma_i32_16x16x64_i8(ah[s][1], P##l1, accB[s], 0, 0, 0); \
            accB[s] = __builtin_amdgcn_mfma_i32_16x16x64_i8(al[s][0], P##h0, accB[s], 0, 0, 0); \
            accB[s] = __builtin_amdgcn_mfma_i32_16x16x64_i8(al[s][1], P##h1, accB[s], 0, 0, 0); \
        } \
        const float sqj_ = P##sv.x; \
        const float cjv_ = P##sv.y; \
        const int   lj_  = __float_as_int(P##sv.z); \
        _Pragma("unroll") \
        for (int s = 0; s < 4; ++s) \
        _Pragma("unroll") \
            for (int t = 0; t < 4; ++t) { \
                int   e  = (accA[s][t] << 8) + accB[s][t]; \
                float ef = (float)e; \
                float mm = cih[s][t] * cjv_; \
                float gg = fmaf(mm, -ef, sqj_); \
                bool same = (li[s][t] == lj_); \
                hpg[s][t] = fmaxf(hpg[s][t], same ? gg : -INFINITY); \
                hng[s][t] = fminf(hng[s][t], same ? INFINITY : gg); \
            } }

    LOADJ(A, 0)
#pragma unroll 1
    for (int it = 0; it < NIT - 2; it += 2) {
        LOADJ(B, it + 1)
        __builtin_amdgcn_sched_barrier(0);
        COMPUTE(A)
        LOADJ(A, it + 2)
        __builtin_amdgcn_sched_barrier(0);
        COMPUTE(B)
    }
    LOADJ(B, NIT - 1)
    __builtin_amdgcn_sched_barrier(0);
    COMPUTE(A)
    COMPUTE(B)
#undef COMPUTE
#undef LOADJ
#undef JROWF

    // reduce over the 16 column-lanes sharing each output row
#pragma unroll
    for (int off = 1; off < 16; off <<= 1)
#pragma unroll
        for (int s = 0; s < 4; ++s)
#pragma unroll
            for (int t = 0; t < 4; ++t) {
                hpg[s][t] = fmaxf(hpg[s][t], __shfl_xor(hpg[s][t], off, 64));
                hng[s][t] = fminf(hng[s][t], __shfl_xor(hng[s][t], off, 64));
            }
    if (lrow == 0) {
#pragma unroll
        for (int s = 0; s < 4; ++s)
#pragma unroll
            for (int t = 0; t < 4; ++t) {
                int i = i0 + w * 64 + s * 16 + lk * 4 + t;
                atomicMax(&hpK[i], fkey(hpg[s][t]));   // order-independent => deterministic
                atomicMin(&hnK[i], fkey(hng[s][t]));
            }
    }
}

__global__ __launch_bounds__(1024)
void final_k(const unsigned* __restrict__ hpK, const unsigned* __restrict__ hnK,
             const float4* __restrict__ sjc, float* __restrict__ out) {
    float total = 0.f, cnt = 0.f;
    for (int i = threadIdx.x; i < NN; i += 1024) {
        float hp = fkey_inv(hpK[i]);
        float hn = fkey_inv(hnK[i]);
        float s  = sjc[i].x;
        float hp2 = s + hp, hn2 = s + hn;                 // d^2 = sq_i + g
        float hpd = (hp2 == -INFINITY) ? -INFINITY : sqrtf(fmaxf(hp2, 0.f));
        float hnd = (hn2 ==  INFINITY) ?  INFINITY : sqrtf(fmaxf(hn2, 0.f));
        float tl = hpd - hnd + 1.0f;                      // -inf propagates, no NaN
        if (tl > 0.f) { total += tl; cnt += 1.f; }
    }
#pragma unroll
    for (int off = 1; off < 64; off <<= 1) {
        total += __shfl_xor(total, off, 64);
        cnt   += __shfl_xor(cnt,   off, 64);
    }
    __shared__ float sT[16], sC[16];
    int wave = threadIdx.x >> 6;
    if ((threadIdx.x & 63) == 0) { sT[wave] = total; sC[wave] = cnt; }
    __syncthreads();
    if (threadIdx.x == 0) {
        float T = 0.f, Cn = 0.f;
#pragma unroll
        for (int k = 0; k < 16; ++k) { T += sT[k]; Cn += sC[k]; }
        out[0] = (Cn > 0.f) ? T / Cn : 0.f;
    }
}

extern "C" void kernel_launch(void* const* d_in, const int* in_sizes, int n_in,
                              void* d_out, int out_size, void* d_ws, size_t ws_size,
                              hipStream_t stream) {
    const float* emb = (const float*)d_in[0];
    const int*   lab = (const int*)d_in[1];
    char* ws = (char*)d_ws;
    float4*   sjc = (float4*)(ws + WS_SJC);
    unsigned* hpK = (unsigned*)(ws + WS_HPK);
    unsigned* hnK = (unsigned*)(ws + WS_HNK);
    int*      aH  = (int*)(ws + WS_AH);
    int*      aL  = (int*)(ws + WS_AL);

    prepq_k<<<dim3(NN / 8), dim3(256), 0, stream>>>(emb, lab, sjc, hpK, hnK, aH, aL);
    hardest_k<<<dim3((NN / BM) * NPART), dim3(256), 0, stream>>>(aH, aL, sjc, hpK, hnK);
    final_k<<<dim3(1), dim3(1024), 0, stream>>>(hpK, hnK, sjc, (float*)d_out);
}